// Round 14
// baseline (1545.214 us; speedup 1.0000x reference)
//
#include <hip/hip_runtime.h>
#include <hip/hip_bf16.h>
#include <stdint.h>
#include <stddef.h>

// ---------------- problem dims (fixed by setup_inputs) ----------------
#define M_DIM 8192
#define K_DIM 4096
#define N_DIM 16384

#define BM 256
#define BN 256
#define BK 64
#define KT (K_DIM / BK)         // 64 K-tiles
#define SLOT_SH (BM * BK)       // 16384 shorts = 32 KB per A slot

typedef __attribute__((ext_vector_type(8))) short bf16x8;  // 8 bf16 = 4 VGPRs
typedef __attribute__((ext_vector_type(4))) float f32x4;
typedef __attribute__((ext_vector_type(4))) int   i32x4;

// fp32 -> bf16, round-to-nearest-even (inputs finite)
static __device__ __forceinline__ short f2bf(float f) {
    union { float f; uint32_t u; } v; v.f = f;
    uint32_t r = v.u + 0x7FFFu + ((v.u >> 16) & 1u);
    return (short)(r >> 16);
}

// FP4 E2M1 decode: low 3 bits magnitude code, bit 3 sign.
static __device__ __forceinline__ float e2m1(int v) {
    int e = (v >> 1) & 3;
    int m = v & 1;
    float mag = (e == 0) ? 0.5f * (float)m
                         : (float)(2 + m) * 0.25f * (float)(1 << e);
    return (v & 8) ? -mag : mag;
}

// async global->LDS, 16 bytes per lane; LDS dest is wave-uniform base + lane*16
static __device__ __forceinline__ void gload16(short* lds, const short* g) {
    __builtin_amdgcn_global_load_lds(
        (const __attribute__((address_space(1))) void*)g,
        (__attribute__((address_space(3))) void*)lds,
        16, 0, 0);
}

// ---------------- kernel 1: x fp32 -> bf16 ----------------
__global__ void cast_x_kernel(const float* __restrict__ x, short* __restrict__ xb) {
    size_t i = (size_t)blockIdx.x * 256 + threadIdx.x;   // one short8 per thread
    const float4* s = reinterpret_cast<const float4*>(x);
    float4 a = s[2 * i];
    float4 b = s[2 * i + 1];
    bf16x8 o;
    o[0] = f2bf(a.x); o[1] = f2bf(a.y); o[2] = f2bf(a.z); o[3] = f2bf(a.w);
    o[4] = f2bf(b.x); o[5] = f2bf(b.y); o[6] = f2bf(b.z); o[7] = f2bf(b.w);
    reinterpret_cast<bf16x8*>(xb)[i] = o;
}

// ---------------- kernel 2: dequant w_q -> bf16 [N, K] ----------------
__global__ void dequant_w_kernel(const int* __restrict__ wq,
                                 const float* __restrict__ wos,
                                 const float* __restrict__ wis,
                                 short* __restrict__ wb) {
    int tid = blockIdx.x * 256 + threadIdx.x;    // N*(K/16) = 4,194,304 total
    int n   = tid >> 8;                          // K/16 = 256 inner blocks per row
    int blk = tid & 255;
    float scale = wis[(n << 8) | blk] * wos[(n << 5) | (blk >> 3)];
    const i32x4* q = reinterpret_cast<const i32x4*>(wq + ((size_t)n << 11) + (blk << 3));
    i32x4 q0 = q[0], q1 = q[1];
    bf16x8 o0, o1;
#pragma unroll
    for (int j = 0; j < 4; ++j) {
        int c = q0[j];
        o0[2 * j]     = f2bf(e2m1(c & 15) * scale);         // even in-feature
        o0[2 * j + 1] = f2bf(e2m1((c >> 4) & 15) * scale);  // odd in-feature
    }
#pragma unroll
    for (int j = 0; j < 4; ++j) {
        int c = q1[j];
        o1[2 * j]     = f2bf(e2m1(c & 15) * scale);
        o1[2 * j + 1] = f2bf(e2m1((c >> 4) & 15) * scale);
    }
    bf16x8* dst = reinterpret_cast<bf16x8*>(wb) + 2 * (size_t)tid;
    dst[0] = o0;
    dst[1] = o1;
}

// ---------------- kernel 3: C[M,N] = A[M,K] * B[N,K]^T, bf16 in / fp32 out --
// R13: B OPERAND DIRECT FROM GLOBAL (AITER s02 pattern), A via LDS.
// Diagnosis R5-R12: every schedule lands ~5720 cyc/K-tile because the DS
// pipe (192 b128 reads x 12cyc + stage writes ~= 2816 cyc/CU) and the matrix
// pipe (2483 cyc/SIMD) fully serialize; even perfect overlap caps at ~2816.
// Fix: move B's fragment reads OFF the DS pipe. B frags (8 per wave per
// K-tile) are global_load_dwordx4 into register banks, issued ONE K-TILE
// ahead (ping-pong P/Q, static indexing rule #20); the end-of-tile vmcnt(0)
// drains loads issued ~3000 cyc earlier (near-free). L1/L2 serve repeats:
// wm-pairs share frag lines (L1); per XCD the co-resident blocks touch
// ~256 KB of B per k-slice (L2-resident). New ledger per K-tile: DS 1792,
// VMEM ~1024 (separate pipe), MFMA 2483 -> floor ~2600-2900 even with
// partial overlap; serial worst case 4275 < 5720.
// A side unchanged from R7 (verified conflict-free swizzle, 2-slot ring,
// one barrier per K-tile -- staging targets the opposite slot whose readers
// retired before the previous boundary barrier).
__global__ __launch_bounds__(512)
void gemm_bt_kernel(const short* __restrict__ A,
                    const short* __restrict__ B,
                    float* __restrict__ C) {
    __shared__ __align__(16) short As[2 * SLOT_SH];   // 64 KB (A only)

    // raster: each XCD owns an 8-wide n-stripe, n-fast (R3, FETCH-verified)
    int bid = blockIdx.x;
    int xcd = bid & 7;
    int idx = bid >> 3;          // 0..255
    int im  = idx >> 3;          // 0..31
    int in8 = idx & 7;           // 0..7
    int bm  = im << 8;
    int bn  = ((xcd << 3) + in8) << 8;

    int t    = threadIdx.x;
    int lane = t & 63;
    int w    = t >> 6;           // wave 0..7
    int wm   = w >> 2;           // 0..1
    int wn   = w & 3;            // 0..3
    int fr   = lane & 15;
    int fq   = lane >> 4;
    int wbase = w << 9;          // wave staging base (shorts): w * 512

    // A staging: thread t covers row (t>>3) of each 64-row chunk, slot t&7.
    // pre-swizzled global k-chunk = (t&7) ^ (row&7)   (R6/R7-verified)
    int gcol = (((t & 7) ^ ((t >> 3) & 7)) << 3);        // shorts
    const short* AgB = A + (size_t)(bm + (t >> 3)) * K_DIM + gcol;

    // A read-side swizzled slots (R7-verified conflict-free)
    int s0 = fq ^ (fr & 7);      // kk = 0 chunk (fq)
    int s1 = s0 ^ 4;             // kk = 1 chunk (4+fq)
    int aBase = ((wm << 7) + fr) * 8;    // bf16x8 units

    // B per-lane global base: row = bn + wn*64 + fr, col = fq*8 (shorts)
    const short* Bg = B + (size_t)(bn + (wn << 6) + fr) * K_DIM + (fq << 3);

    f32x4 acc[8][4] = {};

#define STAGE_A(slot_, kt_)                                                   \
    do {                                                                      \
        const short* _s = AgB + (size_t)(kt_) * BK;                           \
        short* _d = As + (slot_) * SLOT_SH + wbase;                           \
        gload16(_d,         _s);                                              \
        gload16(_d + 4096,  _s + (size_t)64  * K_DIM);                        \
        gload16(_d + 8192,  _s + (size_t)128 * K_DIM);                        \
        gload16(_d + 12288, _s + (size_t)192 * K_DIM);                        \
    } while (0)

// load B frag (ni,kk) of K-tile kt_ directly to a register (16B vector load)
#define BFRAG(ni_, kk_, kt_) \
    (*reinterpret_cast<const bf16x8*>(Bg + (size_t)(ni_) * 16 * K_DIM + \
                                      (kk_) * 32 + (size_t)(kt_) * BK))

    bf16x8 bvP[8], bvQ[8];   // ping/pong B banks: [ni*2+kk]

    // prologue: stage A(0); load B(0) into P; drain; sync
    STAGE_A(0, 0);
#pragma unroll
    for (int ni = 0; ni < 4; ++ni) {
        bvP[ni * 2]     = BFRAG(ni, 0, 0);
        bvP[ni * 2 + 1] = BFRAG(ni, 1, 0);
    }
    asm volatile("s_waitcnt vmcnt(0)" ::: "memory");
    __builtin_amdgcn_s_barrier();

    // one K-tile: MFMA on A(cur LDS slot) x bC (regs, loaded last tile);
    // issue bN loads (tile tt+1) + STAGE_A(tt+1); one vmcnt(0)+barrier/tile.
#define TILE(tt, bC, bN)                                                      \
    do {                                                                      \
        int ktn   = ((tt) + 1) & (KT - 1);   /* dead wrap at tt = KT-1 */     \
        int nslot = ((tt) + 1) & 1;                                           \
        const bf16x8* Af = reinterpret_cast<const bf16x8*>(As + ((tt) & 1) * SLOT_SH); \
        bf16x8 ak0[4], ak1[4];                                                \
        /* ph0: A reads mi0-3 (both kk); issue B(tt+1); stage A(tt+1) */      \
        _Pragma("unroll")                                                     \
        for (int mi = 0; mi < 4; ++mi) {                                      \
            ak0[mi] = Af[aBase + mi * 128 + s0];                              \
            ak1[mi] = Af[aBase + mi * 128 + s1];                              \
        }                                                                     \
        _Pragma("unroll")                                                     \
        for (int ni = 0; ni < 4; ++ni) {                                      \
            bN[ni * 2]     = BFRAG(ni, 0, ktn);                               \
            bN[ni * 2 + 1] = BFRAG(ni, 1, ktn);                               \
        }                                                                     \
        STAGE_A(nslot, ktn);                                                  \
        __builtin_amdgcn_sched_barrier(0);                                    \
        asm volatile("s_waitcnt lgkmcnt(0)" ::: "memory");                    \
        __builtin_amdgcn_sched_barrier(0);                                    \
        __builtin_amdgcn_s_setprio(1);                                        \
        _Pragma("unroll")                                                     \
        for (int mi = 0; mi < 4; ++mi)                                        \
            _Pragma("unroll")                                                 \
            for (int ni = 0; ni < 4; ++ni) {                                  \
                acc[mi][ni] = __builtin_amdgcn_mfma_f32_16x16x32_bf16(        \
                    ak0[mi], bC[ni * 2], acc[mi][ni], 0, 0, 0);               \
                acc[mi][ni] = __builtin_amdgcn_mfma_f32_16x16x32_bf16(        \
                    ak1[mi], bC[ni * 2 + 1], acc[mi][ni], 0, 0, 0);           \
            }                                                                 \
        __builtin_amdgcn_s_setprio(0);                                        \
        /* ph1: A reads mi4-7; MFMA */                                        \
        _Pragma("unroll")                                                     \
        for (int mi = 0; mi < 4; ++mi) {                                      \
            ak0[mi] = Af[aBase + (mi + 4) * 128 + s0];                        \
            ak1[mi] = Af[aBase + (mi + 4) * 128 + s1];                        \
        }                                                                     \
        __builtin_amdgcn_sched_barrier(0);                                    \
        asm volatile("s_waitcnt lgkmcnt(0)" ::: "memory");                    \
        __builtin_amdgcn_sched_barrier(0);                                    \
        __builtin_amdgcn_s_setprio(1);                                        \
        _Pragma("unroll")                                                     \
        for (int mi = 0; mi < 4; ++mi)                                        \
            _Pragma("unroll")                                                 \
            for (int ni = 0; ni < 4; ++ni) {                                  \
                acc[mi + 4][ni] = __builtin_amdgcn_mfma_f32_16x16x32_bf16(    \
                    ak0[mi], bC[ni * 2], acc[mi + 4][ni], 0, 0, 0);           \
                acc[mi + 4][ni] = __builtin_amdgcn_mfma_f32_16x16x32_bf16(    \
                    ak1[mi], bC[ni * 2 + 1], acc[mi + 4][ni], 0, 0, 0);       \
            }                                                                 \
        __builtin_amdgcn_s_setprio(0);                                        \
        /* boundary: drains A-stage + B-frag loads issued ~1 tile ago */      \
        asm volatile("s_waitcnt vmcnt(0)" ::: "memory");                      \
        __builtin_amdgcn_s_barrier();                                         \
    } while (0)

    for (int tt = 0; tt < KT; tt += 2) {
        TILE(tt,     bvP, bvQ);
        TILE(tt + 1, bvQ, bvP);
    }
#undef TILE
#undef BFRAG
#undef STAGE_A

    // epilogue: C/D layout col = lane&15, row = (lane>>4)*4 + reg
#pragma unroll
    for (int mi = 0; mi < 8; ++mi) {
#pragma unroll
        for (int j = 0; j < 4; ++j) {
            size_t row = (size_t)(bm + (wm << 7) + mi * 16 + fq * 4 + j);
            float* Crow = C + row * N_DIM + (bn + (wn << 6) + fr);
#pragma unroll
            for (int ni = 0; ni < 4; ++ni)
                Crow[ni * 16] = acc[mi][ni][j];
        }
    }
}

// ---------------- launch ----------------
extern "C" void kernel_launch(void* const* d_in, const int* in_sizes, int n_in,
                              void* d_out, int out_size, void* d_ws, size_t ws_size,
                              hipStream_t stream) {
    const float* x   = (const float*)d_in[0];
    const int*   wq  = (const int*)d_in[1];
    const float* wos = (const float*)d_in[2];
    const float* wis = (const float*)d_in[3];
    float* out = (float*)d_out;

    short* xb = (short*)d_ws;                                        // 64 MB
    short* wb = (short*)((char*)d_ws + (size_t)M_DIM * K_DIM * 2);   // 128 MB

    cast_x_kernel<<<(M_DIM * (size_t)K_DIM / 8) / 256, 256, 0, stream>>>(x, xb);
    dequant_w_kernel<<<(N_DIM * (size_t)K_DIM / 16) / 256, 256, 0, stream>>>(wq, wos, wis, wb);
    gemm_bt_kernel<<<(M_DIM / BM) * (N_DIM / BN), 512, 0, stream>>>(xb, wb, out);
}

// Round 15
// 1332.360 us; speedup vs baseline: 1.1598x; 1.1598x over previous
//
#include <hip/hip_runtime.h>
#include <hip/hip_bf16.h>
#include <stdint.h>
#include <stddef.h>

// ---------------- problem dims (fixed by setup_inputs) ----------------
#define M_DIM 8192
#define K_DIM 4096
#define N_DIM 16384

#define BM 256
#define BN 256
#define BK 32
#define KSTEPS (K_DIM / BK)     // 128 K-tiles
#define SLOT_SH (BM * BK)       // 8192 shorts = 16 KB per matrix per slot
#define NSLOT 4                 // ring; stage distance 3

typedef __attribute__((ext_vector_type(8))) short bf16x8;  // 8 bf16 = 4 VGPRs
typedef __attribute__((ext_vector_type(4))) float f32x4;
typedef __attribute__((ext_vector_type(4))) int   i32x4;

// fp32 -> bf16, round-to-nearest-even (inputs finite)
static __device__ __forceinline__ short f2bf(float f) {
    union { float f; uint32_t u; } v; v.f = f;
    uint32_t r = v.u + 0x7FFFu + ((v.u >> 16) & 1u);
    return (short)(r >> 16);
}

// FP4 E2M1 decode: low 3 bits magnitude code, bit 3 sign.
static __device__ __forceinline__ float e2m1(int v) {
    int e = (v >> 1) & 3;
    int m = v & 1;
    float mag = (e == 0) ? 0.5f * (float)m
                         : (float)(2 + m) * 0.25f * (float)(1 << e);
    return (v & 8) ? -mag : mag;
}

// async global->LDS, 16 bytes per lane; LDS dest is wave-uniform base + lane*16
static __device__ __forceinline__ void gload16(short* lds, const short* g) {
    __builtin_amdgcn_global_load_lds(
        (const __attribute__((address_space(1))) void*)g,
        (__attribute__((address_space(3))) void*)lds,
        16, 0, 0);
}

// ---------------- kernel 1: x fp32 -> bf16 ----------------
__global__ void cast_x_kernel(const float* __restrict__ x, short* __restrict__ xb) {
    size_t i = (size_t)blockIdx.x * 256 + threadIdx.x;   // one short8 per thread
    const float4* s = reinterpret_cast<const float4*>(x);
    float4 a = s[2 * i];
    float4 b = s[2 * i + 1];
    bf16x8 o;
    o[0] = f2bf(a.x); o[1] = f2bf(a.y); o[2] = f2bf(a.z); o[3] = f2bf(a.w);
    o[4] = f2bf(b.x); o[5] = f2bf(b.y); o[6] = f2bf(b.z); o[7] = f2bf(b.w);
    reinterpret_cast<bf16x8*>(xb)[i] = o;
}

// ---------------- kernel 2: dequant w_q -> bf16 [N, K] ----------------
__global__ void dequant_w_kernel(const int* __restrict__ wq,
                                 const float* __restrict__ wos,
                                 const float* __restrict__ wis,
                                 short* __restrict__ wb) {
    int tid = blockIdx.x * 256 + threadIdx.x;    // N*(K/16) = 4,194,304 total
    int n   = tid >> 8;                          // K/16 = 256 inner blocks per row
    int blk = tid & 255;
    float scale = wis[(n << 8) | blk] * wos[(n << 5) | (blk >> 3)];
    const i32x4* q = reinterpret_cast<const i32x4*>(wq + ((size_t)n << 11) + (blk << 3));
    i32x4 q0 = q[0], q1 = q[1];
    bf16x8 o0, o1;
#pragma unroll
    for (int j = 0; j < 4; ++j) {
        int c = q0[j];
        o0[2 * j]     = f2bf(e2m1(c & 15) * scale);         // even in-feature
        o0[2 * j + 1] = f2bf(e2m1((c >> 4) & 15) * scale);  // odd in-feature
    }
#pragma unroll
    for (int j = 0; j < 4; ++j) {
        int c = q1[j];
        o1[2 * j]     = f2bf(e2m1(c & 15) * scale);
        o1[2 * j + 1] = f2bf(e2m1((c >> 4) & 15) * scale);
    }
    bf16x8* dst = reinterpret_cast<bf16x8*>(wb) + 2 * (size_t)tid;
    dst[0] = o0;
    dst[1] = o1;
}

// ---------------- kernel 3: C[M,N] = A[M,K] * B[N,K]^T, bf16 in / fp32 out --
// R14: FAT WAVES -- 4 waves (2x2), 128x128 output per wave, 1 wave/SIMD.
// Rationale (R5-R13 ledger): with 8 thin waves, A is LDS-re-read 4x and B 2x
// (192 b128/K-tile); every schedule serialized DS vs MFMA. Fat waves halve
// redundancy (128 b128/K-tile, -33% DS) and give each SIMD exactly one wave
// whose 64 MFMA/tile (~1082 cyc) hides its own 16 reads (~192 cyc) via
// one-phase register read-ahead. acc 8x8xf32x4 = 256 regs + 4 frag banks
// ~128 -> ~410 regs, legal at 1 wave/SIMD (launch_bounds(256,1); m08: no
// spill through ~450).
// Pipeline: 4-slot ring, stage distance 3, counted vmcnt(8) per tile
// boundary (never 0 in-loop). Residency: stage(X) issued during X-3;
// boundary vmcnt(8) at end of X-2 leaves only stage(X+1) outstanding =>
// tile X drained before X-1's ph1 read-ahead. Stage slot (t+3)&3 =
// (t-1)&3: its readers retired before boundary t-1. Banks ping-pong by
// tile parity (unroll-2, static names). Per tile: ph0 {read Bhi; stage A;
// 32 MFMA AxBlo}, ph1 {read A',Blo' (tile t+1); stage B; 32 MFMA AxBhi},
// boundary {vmcnt(8); s_barrier}. Swizzle / raster / C-layout verified.
__global__ __launch_bounds__(256, 1)
void gemm_bt_kernel(const short* __restrict__ A,
                    const short* __restrict__ B,
                    float* __restrict__ C) {
    __shared__ __align__(16) short As[NSLOT * SLOT_SH];   // 64 KB
    __shared__ __align__(16) short Bs[NSLOT * SLOT_SH];   // 64 KB

    // raster: each XCD owns an 8-wide n-stripe, n-fast (R3, FETCH-verified)
    int bid = blockIdx.x;
    int xcd = bid & 7;
    int idx = bid >> 3;          // 0..255
    int im  = idx >> 3;          // 0..31
    int in8 = idx & 7;           // 0..7
    int bm  = im << 8;
    int bn  = ((xcd << 3) + in8) << 8;

    int t    = threadIdx.x;      // 0..255
    int lane = t & 63;
    int w    = t >> 6;           // wave 0..3
    int wm   = w >> 1;           // 0..1
    int wn   = w & 1;            // 0..1
    int fr   = lane & 15;
    int fq   = lane >> 4;
    int wbase = w << 9;          // wave staging base: w*16 rows * 32 shorts

    // staging: thread t covers row (t>>2) of each 64-row chunk, 16B slot t&3.
    // pre-swizzled global k-chunk = (t&3) ^ ((row>>1)&3)  (R4-verified, 0 conf)
    int gcol = (((t & 3) ^ ((t >> 3) & 3)) << 3);        // shorts
    const short* AgB = A + (size_t)(bm + (t >> 2)) * K_DIM + gcol;
    const short* BgB = B + (size_t)(bn + (t >> 2)) * K_DIM + gcol;

    // read-side swizzled slot (constant per lane): fq ^ ((fr>>1)&3)
    int slot = fq ^ ((fr >> 1) & 3);
    int aoff[8], boff[8];
#pragma unroll
    for (int mi = 0; mi < 8; ++mi)
        aoff[mi] = ((wm << 7) + mi * 16 + fr) * 4 + slot;
#pragma unroll
    for (int ni = 0; ni < 8; ++ni)
        boff[ni] = ((wn << 7) + ni * 16 + fr) * 4 + slot;

    f32x4 acc[8][8] = {};

    // one matrix K-tile = 16 KB = 4 gloads (256 thr x 16 B = 4 KB each)
#define STAGE_A(slot_, kt_)                                                   \
    do {                                                                      \
        const short* _s = AgB + (size_t)(kt_) * BK;                           \
        short* _d = As + (slot_) * SLOT_SH + wbase;                           \
        gload16(_d,        _s);                                               \
        gload16(_d + 2048, _s + (size_t)64  * K_DIM);                         \
        gload16(_d + 4096, _s + (size_t)128 * K_DIM);                         \
        gload16(_d + 6144, _s + (size_t)192 * K_DIM);                         \
    } while (0)
#define STAGE_B(slot_, kt_)                                                   \
    do {                                                                      \
        const short* _s = BgB + (size_t)(kt_) * BK;                           \
        short* _d = Bs + (slot_) * SLOT_SH + wbase;                           \
        gload16(_d,        _s);                                               \
        gload16(_d + 2048, _s + (size_t)64  * K_DIM);                         \
        gload16(_d + 4096, _s + (size_t)128 * K_DIM);                         \
        gload16(_d + 6144, _s + (size_t)192 * K_DIM);                         \
    } while (0)

    // fragment banks (static names; parity by tile -- unroll 2)
    bf16x8 aP[8], bloP[4], bhiP[4];
    bf16x8 aQ[8], bloQ[4], bhiQ[4];

    // prologue: stage tiles 0,1,2; drain tiles 0+1 (vmcnt(8) leaves tile2's
    // 8 newest); read tile 0's A + Blo into P banks.
    STAGE_A(0, 0); STAGE_B(0, 0);
    STAGE_A(1, 1); STAGE_B(1, 1);
    STAGE_A(2, 2); STAGE_B(2, 2);
    asm volatile("s_waitcnt vmcnt(8)" ::: "memory");
    __builtin_amdgcn_s_barrier();
    __builtin_amdgcn_sched_barrier(0);
    {
        const bf16x8* Af = reinterpret_cast<const bf16x8*>(As);
        const bf16x8* Bf = reinterpret_cast<const bf16x8*>(Bs);
#pragma unroll
        for (int mi = 0; mi < 8; ++mi) aP[mi] = Af[aoff[mi]];
#pragma unroll
        for (int ni = 0; ni < 4; ++ni) bloP[ni] = Bf[boff[ni]];
    }

// TILE(tt): banks C = current parity, N = next parity.
#define TILE(tt, aC, bloC, bhiC, aN, bloN)                                    \
    do {                                                                      \
        int ktn  = ((tt) + 3) & (KSTEPS - 1);   /* dead wrap tt>=125 */       \
        int sStg = ((tt) + 3) & 3;                                            \
        const bf16x8* AfC = reinterpret_cast<const bf16x8*>(As + ((tt) & 3) * SLOT_SH); \
        const bf16x8* BfC = reinterpret_cast<const bf16x8*>(Bs + ((tt) & 3) * SLOT_SH); \
        const bf16x8* AfN = reinterpret_cast<const bf16x8*>(As + (((tt) + 1) & 3) * SLOT_SH); \
        const bf16x8* BfN = reinterpret_cast<const bf16x8*>(Bs + (((tt) + 1) & 3) * SLOT_SH); \
        /* ph0: read Bhi (this tile); stage A(tt+3); MFMA A x Blo */          \
        _Pragma("unroll")                                                     \
        for (int ni = 0; ni < 4; ++ni) bhiC[ni] = BfC[boff[ni + 4]];          \
        STAGE_A(sStg, ktn);                                                   \
        __builtin_amdgcn_sched_barrier(0);                                    \
        _Pragma("unroll")                                                     \
        for (int mi = 0; mi < 8; ++mi)                                        \
            _Pragma("unroll")                                                 \
            for (int ni = 0; ni < 4; ++ni)                                    \
                acc[mi][ni] = __builtin_amdgcn_mfma_f32_16x16x32_bf16(        \
                    aC[mi], bloC[ni], acc[mi][ni], 0, 0, 0);                  \
        __builtin_amdgcn_sched_barrier(0);                                    \
        /* ph1: read A',Blo' (tile tt+1); stage B(tt+3); MFMA A x Bhi */      \
        _Pragma("unroll")                                                     \
        for (int mi = 0; mi < 8; ++mi) aN[mi] = AfN[aoff[mi]];                \
        _Pragma("unroll")                                                     \
        for (int ni = 0; ni < 4; ++ni) bloN[ni] = BfN[boff[ni]];              \
        STAGE_B(sStg, ktn);                                                   \
        __builtin_amdgcn_sched_barrier(0);                                    \
        _Pragma("unroll")                                                     \
        for (int mi = 0; mi < 8; ++mi)                                        \
            _Pragma("unroll")                                                 \
            for (int ni = 0; ni < 4; ++ni)                                    \
                acc[mi][ni + 4] = __builtin_amdgcn_mfma_f32_16x16x32_bf16(    \
                    aC[mi], bhiC[ni], acc[mi][ni + 4], 0, 0, 0);              \
        /* boundary: counted drain (leaves stage(tt+3)'s 8), sync */          \
        asm volatile("s_waitcnt vmcnt(8)" ::: "memory");                      \
        __builtin_amdgcn_s_barrier();                                         \
        __builtin_amdgcn_sched_barrier(0);                                    \
    } while (0)

    for (int tt = 0; tt < KSTEPS; tt += 2) {
        TILE(tt,     aP, bloP, bhiP, aQ, bloQ);
        TILE(tt + 1, aQ, bloQ, bhiQ, aP, bloP);
    }
#undef TILE
#undef STAGE_A
#undef STAGE_B

    // epilogue: C/D layout col = lane&15, row = (lane>>4)*4 + reg
#pragma unroll
    for (int mi = 0; mi < 8; ++mi) {
#pragma unroll
        for (int j = 0; j < 4; ++j) {
            size_t row = (size_t)(bm + (wm << 7) + mi * 16 + fq * 4 + j);
            float* Crow = C + row * N_DIM + (bn + (wn << 7) + fr);
#pragma unroll
            for (int ni = 0; ni < 8; ++ni)
                Crow[ni * 16] = acc[mi][ni][j];
        }
    }
}

// ---------------- launch ----------------
extern "C" void kernel_launch(void* const* d_in, const int* in_sizes, int n_in,
                              void* d_out, int out_size, void* d_ws, size_t ws_size,
                              hipStream_t stream) {
    const float* x   = (const float*)d_in[0];
    const int*   wq  = (const int*)d_in[1];
    const float* wos = (const float*)d_in[2];
    const float* wis = (const float*)d_in[3];
    float* out = (float*)d_out;

    short* xb = (short*)d_ws;                                        // 64 MB
    short* wb = (short*)((char*)d_ws + (size_t)M_DIM * K_DIM * 2);   // 128 MB

    cast_x_kernel<<<(M_DIM * (size_t)K_DIM / 8) / 256, 256, 0, stream>>>(x, xb);
    dequant_w_kernel<<<(N_DIM * (size_t)K_DIM / 16) / 256, 256, 0, stream>>>(wq, wos, wis, wb);
    gemm_bt_kernel<<<(M_DIM / BM) * (N_DIM / BN), 256, 0, stream>>>(xb, wb, out);
}

// Round 16
// 1167.501 us; speedup vs baseline: 1.3235x; 1.1412x over previous
//
#include <hip/hip_runtime.h>
#include <hip/hip_bf16.h>
#include <stdint.h>
#include <stddef.h>

// ---------------- problem dims (fixed by setup_inputs) ----------------
#define M_DIM 8192
#define K_DIM 4096
#define N_DIM 16384

#define BM 256
#define BN 256
#define BK 64
#define KT (K_DIM / BK)         // 64 K-tiles
#define SLOT_SH (BM * BK)       // 16384 shorts = 32 KB per matrix per slot

typedef __attribute__((ext_vector_type(8))) short bf16x8;  // 8 bf16 = 4 VGPRs
typedef __attribute__((ext_vector_type(4))) float f32x4;
typedef __attribute__((ext_vector_type(4))) int   i32x4;

// fp32 -> bf16, round-to-nearest-even (inputs finite)
static __device__ __forceinline__ short f2bf(float f) {
    union { float f; uint32_t u; } v; v.f = f;
    uint32_t r = v.u + 0x7FFFu + ((v.u >> 16) & 1u);
    return (short)(r >> 16);
}

// FP4 E2M1 decode: low 3 bits magnitude code, bit 3 sign.
static __device__ __forceinline__ float e2m1(int v) {
    int e = (v >> 1) & 3;
    int m = v & 1;
    float mag = (e == 0) ? 0.5f * (float)m
                         : (float)(2 + m) * 0.25f * (float)(1 << e);
    return (v & 8) ? -mag : mag;
}

// async global->LDS, 16 bytes per lane; LDS dest is wave-uniform base + lane*16
static __device__ __forceinline__ void gload16(short* lds, const short* g) {
    __builtin_amdgcn_global_load_lds(
        (const __attribute__((address_space(1))) void*)g,
        (__attribute__((address_space(3))) void*)lds,
        16, 0, 0);
}

// ---------------- kernel 1: x fp32 -> bf16 ----------------
__global__ void cast_x_kernel(const float* __restrict__ x, short* __restrict__ xb) {
    size_t i = (size_t)blockIdx.x * 256 + threadIdx.x;   // one short8 per thread
    const float4* s = reinterpret_cast<const float4*>(x);
    float4 a = s[2 * i];
    float4 b = s[2 * i + 1];
    bf16x8 o;
    o[0] = f2bf(a.x); o[1] = f2bf(a.y); o[2] = f2bf(a.z); o[3] = f2bf(a.w);
    o[4] = f2bf(b.x); o[5] = f2bf(b.y); o[6] = f2bf(b.z); o[7] = f2bf(b.w);
    reinterpret_cast<bf16x8*>(xb)[i] = o;
}

// ---------------- kernel 2: dequant w_q -> bf16 [N, K] ----------------
__global__ void dequant_w_kernel(const int* __restrict__ wq,
                                 const float* __restrict__ wos,
                                 const float* __restrict__ wis,
                                 short* __restrict__ wb) {
    int tid = blockIdx.x * 256 + threadIdx.x;    // N*(K/16) = 4,194,304 total
    int n   = tid >> 8;                          // K/16 = 256 inner blocks per row
    int blk = tid & 255;
    float scale = wis[(n << 8) | blk] * wos[(n << 5) | (blk >> 3)];
    const i32x4* q = reinterpret_cast<const i32x4*>(wq + ((size_t)n << 11) + (blk << 3));
    i32x4 q0 = q[0], q1 = q[1];
    bf16x8 o0, o1;
#pragma unroll
    for (int j = 0; j < 4; ++j) {
        int c = q0[j];
        o0[2 * j]     = f2bf(e2m1(c & 15) * scale);         // even in-feature
        o0[2 * j + 1] = f2bf(e2m1((c >> 4) & 15) * scale);  // odd in-feature
    }
#pragma unroll
    for (int j = 0; j < 4; ++j) {
        int c = q1[j];
        o1[2 * j]     = f2bf(e2m1(c & 15) * scale);
        o1[2 * j + 1] = f2bf(e2m1((c >> 4) & 15) * scale);
    }
    bf16x8* dst = reinterpret_cast<bf16x8*>(wb) + 2 * (size_t)tid;
    dst[0] = o0;
    dst[1] = o1;
}

// ---------------- kernel 3: C[M,N] = A[M,K] * B[N,K]^T, bf16 in / fp32 out --
// R15: ONE-QUADRANT REGISTER READ-AHEAD + compiler-counted lgkm.
// R5-R14 invariant diagnosed: every MFMA cluster lgkm-waited on ds_reads
// issued in the SAME phase -> DS drain (~770-1150 cyc) then MFMA (~620)
// serialized per phase ~= 1425 cyc, 4x per K-tile = the stuck 5700.
// Fix: within the R11 minimal-sync skeleton (BK=64, 2 slots, ONE vmcnt(0)
// + ONE s_barrier per K-tile, both draining ops issued ~2500 cyc earlier),
// issue quadrant q+1's reads BEFORE cluster q's MFMAs (program order, one
// sched_barrier(0) per boundary). Cluster q consumes banks read a quadrant
// ago; the compiler emits COUNTED lgkmcnt (m97 behavior) so the DS drain of
// q+1 overlaps cluster q. DS/region 384-768 cyc vs MFMA 620 -> balanced.
// Banks: static names, each written exactly one cluster before its consumer
// (rule #20; WAR safe by in-order issue).
//   tile T (slot s=T&1): STAGE(T+1 -> s^1);
//     [reads aB1<-A(mi4-7,kk0)] [MFMA Q0: acc[0-3] += aB0 x bB0]
//     [reads aB0<-A(mi0-3,kk1), bB1<-B(kk1)] [MFMA Q1: acc[4-7] += aB1 x bB0]
//     [reads aB1<-A(mi4-7,kk1)] [MFMA Q2: acc[0-3] += aB0 x bB1]
//     lgkmcnt(0) (drain own reads, ~620cyc old -> free; protects slot s from
//     next tile's gloads); vmcnt(0) (T+1's stages, ~2500cyc old -> free);
//     s_barrier;
//     [reads aB0,bB0 <- tile T+1 slot s^1 (Q0')] [MFMA Q3: acc[4-7] += aB1 x bB1]
// Wrap at kt=63: Q0'/stage touch dead data only, race-free.
// Swizzle (0 conflicts), raster, epilogue verified unchanged.
__global__ __launch_bounds__(512)
void gemm_bt_kernel(const short* __restrict__ A,
                    const short* __restrict__ B,
                    float* __restrict__ C) {
    __shared__ __align__(16) short As[2 * SLOT_SH];   // 64 KB
    __shared__ __align__(16) short Bs[2 * SLOT_SH];   // 64 KB

    // raster: each XCD owns an 8-wide n-stripe, n-fast (R3, FETCH-verified)
    int bid = blockIdx.x;
    int xcd = bid & 7;
    int idx = bid >> 3;          // 0..255
    int im  = idx >> 3;          // 0..31
    int in8 = idx & 7;           // 0..7
    int bm  = im << 8;
    int bn  = ((xcd << 3) + in8) << 8;

    int t    = threadIdx.x;
    int lane = t & 63;
    int w    = t >> 6;           // wave 0..7
    int wm   = w >> 2;           // 0..1
    int wn   = w & 3;            // 0..3
    int fr   = lane & 15;
    int fq   = lane >> 4;
    int wbase = w << 9;          // wave staging base (shorts): w * 512

    // staging: thread t covers row (t>>3) of each 64-row chunk, 16B slot t&7.
    // pre-swizzled global k-chunk = (t&7) ^ (row&7)   (R6/R7-verified)
    int gcol = (((t & 7) ^ ((t >> 3) & 7)) << 3);        // shorts
    const short* AgB = A + (size_t)(bm + (t >> 3)) * K_DIM + gcol;
    const short* BgB = B + (size_t)(bn + (t >> 3)) * K_DIM + gcol;

    // read-side swizzled slots: frag (kk,fq) needs global chunk kk*4+fq at
    // row ...+fr  ->  stored slot = (kk*4+fq) ^ (fr&7)
    int s0 = fq ^ (fr & 7);      // kk = 0
    int s1 = s0 ^ 4;             // kk = 1
    int aBase = ((wm << 7) + fr) * 8;    // bf16x8 units
    int bBase = ((wn << 6) + fr) * 8;

    f32x4 acc[8][4] = {};

#define STAGE_A(slot_, kt_)                                                   \
    do {                                                                      \
        const short* _s = AgB + (size_t)(kt_) * BK;                           \
        short* _d = As + (slot_) * SLOT_SH + wbase;                           \
        gload16(_d,         _s);                                              \
        gload16(_d + 4096,  _s + (size_t)64  * K_DIM);                        \
        gload16(_d + 8192,  _s + (size_t)128 * K_DIM);                        \
        gload16(_d + 12288, _s + (size_t)192 * K_DIM);                        \
    } while (0)
#define STAGE_B(slot_, kt_)                                                   \
    do {                                                                      \
        const short* _s = BgB + (size_t)(kt_) * BK;                           \
        short* _d = Bs + (slot_) * SLOT_SH + wbase;                           \
        gload16(_d,         _s);                                              \
        gload16(_d + 4096,  _s + (size_t)64  * K_DIM);                        \
        gload16(_d + 8192,  _s + (size_t)128 * K_DIM);                        \
        gload16(_d + 12288, _s + (size_t)192 * K_DIM);                        \
    } while (0)

    // fragment banks (static names; each written one cluster before use)
    bf16x8 aB0[4], aB1[4], bB0[4], bB1[4];

    // prologue: stage tile 0; drain; read tile-0 Q0 banks
    STAGE_A(0, 0);
    STAGE_B(0, 0);
    asm volatile("s_waitcnt vmcnt(0)" ::: "memory");
    __builtin_amdgcn_s_barrier();
    {
        const bf16x8* Af = reinterpret_cast<const bf16x8*>(As);
        const bf16x8* Bf = reinterpret_cast<const bf16x8*>(Bs);
#pragma unroll
        for (int ni = 0; ni < 4; ++ni) bB0[ni] = Bf[bBase + ni * 128 + s0];
#pragma unroll
        for (int mi = 0; mi < 4; ++mi) aB0[mi] = Af[aBase + mi * 128 + s0];
    }

    for (int kt = 0; kt < KT; ++kt) {
        int c   = kt & 1;
        int ktn = (kt + 1) & (KT - 1);       // dead wrap at kt = KT-1
        const bf16x8* Af  = reinterpret_cast<const bf16x8*>(As + c * SLOT_SH);
        const bf16x8* Bf  = reinterpret_cast<const bf16x8*>(Bs + c * SLOT_SH);
        const bf16x8* AfN = reinterpret_cast<const bf16x8*>(As + (c ^ 1) * SLOT_SH);
        const bf16x8* BfN = reinterpret_cast<const bf16x8*>(Bs + (c ^ 1) * SLOT_SH);

        // stage next tile early (full-tile lead before the boundary vmcnt)
        STAGE_A(c ^ 1, ktn);
        STAGE_B(c ^ 1, ktn);

        // ---- reads Q1 (A mi4-7 kk0) || MFMA Q0 (aB0 x bB0 -> acc[0-3])
#pragma unroll
        for (int mi = 0; mi < 4; ++mi) aB1[mi] = Af[aBase + (mi + 4) * 128 + s0];
        __builtin_amdgcn_sched_barrier(0);
        __builtin_amdgcn_s_setprio(1);
#pragma unroll
        for (int mi = 0; mi < 4; ++mi)
#pragma unroll
            for (int ni = 0; ni < 4; ++ni)
                acc[mi][ni] = __builtin_amdgcn_mfma_f32_16x16x32_bf16(
                    aB0[mi], bB0[ni], acc[mi][ni], 0, 0, 0);
        __builtin_amdgcn_s_setprio(0);

        // ---- reads Q2 (A mi0-3 kk1 + B kk1) || MFMA Q1 (aB1 x bB0 -> acc[4-7])
#pragma unroll
        for (int mi = 0; mi < 4; ++mi) aB0[mi] = Af[aBase + mi * 128 + s1];
#pragma unroll
        for (int ni = 0; ni < 4; ++ni) bB1[ni] = Bf[bBase + ni * 128 + s1];
        __builtin_amdgcn_sched_barrier(0);
        __builtin_amdgcn_s_setprio(1);
#pragma unroll
        for (int mi = 0; mi < 4; ++mi)
#pragma unroll
            for (int ni = 0; ni < 4; ++ni)
                acc[mi + 4][ni] = __builtin_amdgcn_mfma_f32_16x16x32_bf16(
                    aB1[mi], bB0[ni], acc[mi + 4][ni], 0, 0, 0);
        __builtin_amdgcn_s_setprio(0);

        // ---- reads Q3 (A mi4-7 kk1) || MFMA Q2 (aB0 x bB1 -> acc[0-3])
#pragma unroll
        for (int mi = 0; mi < 4; ++mi) aB1[mi] = Af[aBase + (mi + 4) * 128 + s1];
        __builtin_amdgcn_sched_barrier(0);
        __builtin_amdgcn_s_setprio(1);
#pragma unroll
        for (int mi = 0; mi < 4; ++mi)
#pragma unroll
            for (int ni = 0; ni < 4; ++ni)
                acc[mi][ni] = __builtin_amdgcn_mfma_f32_16x16x32_bf16(
                    aB0[mi], bB1[ni], acc[mi][ni], 0, 0, 0);
        __builtin_amdgcn_s_setprio(0);

        // ---- boundary: drain own ds_reads (Q3's, ~620cyc old -> free) so no
        // pending read races next tile's gloads into slot c; drain stages of
        // tile kt+1 (issued ~2500cyc ago -> free); rendezvous.
        asm volatile("s_waitcnt lgkmcnt(0)" ::: "memory");
        __builtin_amdgcn_sched_barrier(0);
        asm volatile("s_waitcnt vmcnt(0)" ::: "memory");
        __builtin_amdgcn_s_barrier();

        // ---- reads Q0' (tile kt+1, slot c^1) || MFMA Q3 (aB1 x bB1 -> acc[4-7])
#pragma unroll
        for (int ni = 0; ni < 4; ++ni) bB0[ni] = BfN[bBase + ni * 128 + s0];
#pragma unroll
        for (int mi = 0; mi < 4; ++mi) aB0[mi] = AfN[aBase + mi * 128 + s0];
        __builtin_amdgcn_sched_barrier(0);
        __builtin_amdgcn_s_setprio(1);
#pragma unroll
        for (int mi = 0; mi < 4; ++mi)
#pragma unroll
            for (int ni = 0; ni < 4; ++ni)
                acc[mi + 4][ni] = __builtin_amdgcn_mfma_f32_16x16x32_bf16(
                    aB1[mi], bB1[ni], acc[mi + 4][ni], 0, 0, 0);
        __builtin_amdgcn_s_setprio(0);
    }
#undef STAGE_A
#undef STAGE_B

    // epilogue: C/D layout col = lane&15, row = (lane>>4)*4 + reg
#pragma unroll
    for (int mi = 0; mi < 8; ++mi) {
#pragma unroll
        for (int j = 0; j < 4; ++j) {
            size_t row = (size_t)(bm + (wm << 7) + mi * 16 + fq * 4 + j);
            float* Crow = C + row * N_DIM + (bn + (wn << 6) + fr);
#pragma unroll
            for (int ni = 0; ni < 4; ++ni)
                Crow[ni * 16] = acc[mi][ni][j];
        }
    }
}

// ---------------- launch ----------------
extern "C" void kernel_launch(void* const* d_in, const int* in_sizes, int n_in,
                              void* d_out, int out_size, void* d_ws, size_t ws_size,
                              hipStream_t stream) {
    const float* x   = (const float*)d_in[0];
    const int*   wq  = (const int*)d_in[1];
    const float* wos = (const float*)d_in[2];
    const float* wis = (const float*)d_in[3];
    float* out = (float*)d_out;

    short* xb = (short*)d_ws;                                        // 64 MB
    short* wb = (short*)((char*)d_ws + (size_t)M_DIM * K_DIM * 2);   // 128 MB

    cast_x_kernel<<<(M_DIM * (size_t)K_DIM / 8) / 256, 256, 0, stream>>>(x, xb);
    dequant_w_kernel<<<(N_DIM * (size_t)K_DIM / 16) / 256, 256, 0, stream>>>(wq, wos, wis, wb);
    gemm_bt_kernel<<<(M_DIM / BM) * (N_DIM / BN), 512, 0, stream>>>(xb, wb, out);
}

// Round 18
// 1162.640 us; speedup vs baseline: 1.3291x; 1.0042x over previous
//
#include <hip/hip_runtime.h>
#include <hip/hip_bf16.h>
#include <stdint.h>
#include <stddef.h>

// ---------------- problem dims (fixed by setup_inputs) ----------------
#define M_DIM 8192
#define K_DIM 4096
#define N_DIM 16384

#define BM 256
#define BN 256
#define BK 32
#define KSTEPS (K_DIM / BK)     // 128 K-tiles
#define SLOT_SH (BM * BK)       // 8192 shorts = 16 KB per matrix per slot
#define NSLOT 4                 // ring; stage distance 3

typedef __attribute__((ext_vector_type(8))) short bf16x8;  // 8 bf16 = 4 VGPRs
typedef __attribute__((ext_vector_type(4))) float f32x4;
typedef __attribute__((ext_vector_type(4))) int   i32x4;

// fp32 -> bf16, round-to-nearest-even (inputs finite)
static __device__ __forceinline__ short f2bf(float f) {
    union { float f; uint32_t u; } v; v.f = f;
    uint32_t r = v.u + 0x7FFFu + ((v.u >> 16) & 1u);
    return (short)(r >> 16);
}

// FP4 E2M1 decode: low 3 bits magnitude code, bit 3 sign.
static __device__ __forceinline__ float e2m1(int v) {
    int e = (v >> 1) & 3;
    int m = v & 1;
    float mag = (e == 0) ? 0.5f * (float)m
                         : (float)(2 + m) * 0.25f * (float)(1 << e);
    return (v & 8) ? -mag : mag;
}

// async global->LDS, 16 bytes per lane; LDS dest is wave-uniform base + lane*16
static __device__ __forceinline__ void gload16(short* lds, const short* g) {
    __builtin_amdgcn_global_load_lds(
        (const __attribute__((address_space(1))) void*)g,
        (__attribute__((address_space(3))) void*)lds,
        16, 0, 0);
}

// ---------------- kernel 1: x fp32 -> bf16 ----------------
__global__ void cast_x_kernel(const float* __restrict__ x, short* __restrict__ xb) {
    size_t i = (size_t)blockIdx.x * 256 + threadIdx.x;   // one short8 per thread
    const float4* s = reinterpret_cast<const float4*>(x);
    float4 a = s[2 * i];
    float4 b = s[2 * i + 1];
    bf16x8 o;
    o[0] = f2bf(a.x); o[1] = f2bf(a.y); o[2] = f2bf(a.z); o[3] = f2bf(a.w);
    o[4] = f2bf(b.x); o[5] = f2bf(b.y); o[6] = f2bf(b.z); o[7] = f2bf(b.w);
    reinterpret_cast<bf16x8*>(xb)[i] = o;
}

// ---------------- kernel 2: dequant w_q -> bf16 [N, K] ----------------
__global__ void dequant_w_kernel(const int* __restrict__ wq,
                                 const float* __restrict__ wos,
                                 const float* __restrict__ wis,
                                 short* __restrict__ wb) {
    int tid = blockIdx.x * 256 + threadIdx.x;    // N*(K/16) = 4,194,304 total
    int n   = tid >> 8;                          // K/16 = 256 inner blocks per row
    int blk = tid & 255;
    float scale = wis[(n << 8) | blk] * wos[(n << 5) | (blk >> 3)];
    const i32x4* q = reinterpret_cast<const i32x4*>(wq + ((size_t)n << 11) + (blk << 3));
    i32x4 q0 = q[0], q1 = q[1];
    bf16x8 o0, o1;
#pragma unroll
    for (int j = 0; j < 4; ++j) {
        int c = q0[j];
        o0[2 * j]     = f2bf(e2m1(c & 15) * scale);         // even in-feature
        o0[2 * j + 1] = f2bf(e2m1((c >> 4) & 15) * scale);  // odd in-feature
    }
#pragma unroll
    for (int j = 0; j < 4; ++j) {
        int c = q1[j];
        o1[2 * j]     = f2bf(e2m1(c & 15) * scale);
        o1[2 * j + 1] = f2bf(e2m1((c >> 4) & 15) * scale);
    }
    bf16x8* dst = reinterpret_cast<bf16x8*>(wb) + 2 * (size_t)tid;
    dst[0] = o0;
    dst[1] = o1;
}

// ---------------- kernel 3: C[M,N] = A[M,K] * B[N,K]^T, bf16 in / fp32 out --
// R17 = R16 (full-tile register read-ahead, 4-slot ring) with the vmcnt
// COUNT BUG fixed. R16 failed correctness (absmax 1.71): each tile stages
// only 4 loads (2A+2B), so the prologue's vmcnt(8) with 12 outstanding
// drained ONLY stage(0) -- tile 0's Q-fill read slot 1 unprotected; the
// in-loop vmcnt(8) with 8 outstanding was a NO-OP -- slot (T+1)&3 was never
// guaranteed resident before its mid-tile read-ahead.
// Fix: vmcnt(4) both places. Corrected audit:
//   prologue: 12 outstanding -> vmcnt(4) drains stages 0,1 (both slots that
//     tile 0 touches). leaves stage(2).
//   end of tile T: outstanding = stage(T+2) [issued T-1, ~1400cyc old] +
//     stage(T+3) [this tile]; vmcnt(4) drains stage(T+2) (counted, never 0,
//     ~free) => slot (T+2)&3 resident before tile T+1's fill reads it.
//   WAR: fills of slot (T+1)&3 (issued T) are lgkm-complete by consumption
//     at T+1 < end-T+1 barrier < staging into that slot at T+2.
// Pipeline intent (R16): consume fragments read a FULL TILE ago -> lgkm
// waits vanish; DS pipe streams under MFMA; floor max(DS 1408, MFMA 1242)
// per K-tile-32. Banks static-named, ping-pong by tile parity (rule #20).
// Swizzle (0 conflicts), raster, epilogue verified.
__global__ __launch_bounds__(512)
void gemm_bt_kernel(const short* __restrict__ A,
                    const short* __restrict__ B,
                    float* __restrict__ C) {
    __shared__ __align__(16) short As[NSLOT * SLOT_SH];   // 64 KB
    __shared__ __align__(16) short Bs[NSLOT * SLOT_SH];   // 64 KB

    // raster: each XCD owns an 8-wide n-stripe, n-fast (R3, FETCH-verified)
    int bid = blockIdx.x;
    int xcd = bid & 7;
    int idx = bid >> 3;          // 0..255
    int im  = idx >> 3;          // 0..31
    int in8 = idx & 7;           // 0..7
    int bm  = im << 8;
    int bn  = ((xcd << 3) + in8) << 8;

    int t    = threadIdx.x;
    int lane = t & 63;
    int w    = t >> 6;           // wave 0..7
    int wm   = w >> 2;           // 0..1
    int wn   = w & 3;            // 0..3
    int fr   = lane & 15;
    int fq   = lane >> 4;
    int wbase = w << 9;          // wave staging base (shorts): w * 512

    // staging: thread t covers row (t>>2) of each 128-row chunk, 16B slot t&3.
    // pre-swizzled global k-chunk = (t&3) ^ ((row>>1)&3)  (R4-verified, 0 conf)
    int gcol = (((t & 3) ^ ((t >> 3) & 3)) << 3);        // shorts
    const short* AgB = A + (size_t)(bm + (t >> 2)) * K_DIM + gcol;
    const short* BgB = B + (size_t)(bn + (t >> 2)) * K_DIM + gcol;

    // read-side swizzled slot (constant per lane): fq ^ ((fr>>1)&3)
    int slot = fq ^ ((fr >> 1) & 3);
    int aoff[8], boff[4];
#pragma unroll
    for (int mi = 0; mi < 8; ++mi)
        aoff[mi] = ((wm << 7) + mi * 16 + fr) * 4 + slot;
#pragma unroll
    for (int ni = 0; ni < 4; ++ni)
        boff[ni] = ((wn << 6) + ni * 16 + fr) * 4 + slot;

    f32x4 acc[8][4] = {};

    // one matrix K-tile = 16 KB = 2 gloads (512 thr x 16 B = 8 KB each)
#define STAGE_A(slot_, kt_)                                                   \
    do {                                                                      \
        const short* _s = AgB + (size_t)(kt_) * BK;                           \
        short* _d = As + (slot_) * SLOT_SH + wbase;                           \
        gload16(_d,        _s);                                               \
        gload16(_d + 4096, _s + (size_t)128 * K_DIM);                         \
    } while (0)
#define STAGE_B(slot_, kt_)                                                   \
    do {                                                                      \
        const short* _s = BgB + (size_t)(kt_) * BK;                           \
        short* _d = Bs + (slot_) * SLOT_SH + wbase;                           \
        gload16(_d,        _s);                                               \
        gload16(_d + 4096, _s + (size_t)128 * K_DIM);                         \
    } while (0)

    // fragment banks: P consumed on even tiles, Q on odd (static names)
    bf16x8 aP[8], bP[4], aQ[8], bQ[4];

    // prologue: stage tiles 0,1,2 (slots 0,1,2; 12 loads); vmcnt(4) drains
    // stages 0 AND 1 (tile 0 reads slot 0 now and slot 1 mid-tile); fill P.
    STAGE_A(0, 0); STAGE_B(0, 0);
    STAGE_A(1, 1); STAGE_B(1, 1);
    STAGE_A(2, 2); STAGE_B(2, 2);
    asm volatile("s_waitcnt vmcnt(4)" ::: "memory");
    __builtin_amdgcn_s_barrier();
    {
        const bf16x8* Af = reinterpret_cast<const bf16x8*>(As);
        const bf16x8* Bf = reinterpret_cast<const bf16x8*>(Bs);
#pragma unroll
        for (int ni = 0; ni < 4; ++ni) bP[ni] = Bf[boff[ni]];
#pragma unroll
        for (int mi = 0; mi < 8; ++mi) aP[mi] = Af[aoff[mi]];
    }

    // TILE(T): consume bank C (filled during T-1 with tile T's frags);
    // fill bank N with tile T+1's frags from slot (T+1)&3; stage tile T+3.
#define TILE(tt, aC, bC, aN, bN)                                              \
    do {                                                                      \
        int ktn  = ((tt) + 3) & (KSTEPS - 1);   /* dead wrap tt>=125 */       \
        int sStg = ((tt) + 3) & 3;                                            \
        const bf16x8* AfN = reinterpret_cast<const bf16x8*>(As + (((tt) + 1) & 3) * SLOT_SH); \
        const bf16x8* BfN = reinterpret_cast<const bf16x8*>(Bs + (((tt) + 1) & 3) * SLOT_SH); \
        STAGE_A(sStg, ktn);                                                   \
        _Pragma("unroll")                                                     \
        for (int ni = 0; ni < 4; ++ni) bN[ni] = BfN[boff[ni]];                \
        _Pragma("unroll")                                                     \
        for (int mi = 0; mi < 4; ++mi) aN[mi] = AfN[aoff[mi]];                \
        __builtin_amdgcn_sched_barrier(0);                                    \
        __builtin_amdgcn_s_setprio(1);                                        \
        _Pragma("unroll")                                                     \
        for (int mi = 0; mi < 4; ++mi)                                        \
            _Pragma("unroll")                                                 \
            for (int ni = 0; ni < 4; ++ni)                                    \
                acc[mi][ni] = __builtin_amdgcn_mfma_f32_16x16x32_bf16(        \
                    aC[mi], bC[ni], acc[mi][ni], 0, 0, 0);                    \
        __builtin_amdgcn_s_setprio(0);                                        \
        __builtin_amdgcn_sched_barrier(0);                                    \
        STAGE_B(sStg, ktn);                                                   \
        _Pragma("unroll")                                                     \
        for (int mi = 4; mi < 8; ++mi) aN[mi] = AfN[aoff[mi]];                \
        __builtin_amdgcn_sched_barrier(0);                                    \
        __builtin_amdgcn_s_setprio(1);                                        \
        _Pragma("unroll")                                                     \
        for (int mi = 4; mi < 8; ++mi)                                        \
            _Pragma("unroll")                                                 \
            for (int ni = 0; ni < 4; ++ni)                                    \
                acc[mi][ni] = __builtin_amdgcn_mfma_f32_16x16x32_bf16(        \
                    aC[mi], bC[ni], acc[mi][ni], 0, 0, 0);                    \
        __builtin_amdgcn_s_setprio(0);                                        \
        /* boundary: drain stage(T+2) (issued one full tile ago, ~free;     */\
        /* counted, never 0) so slot (T+2)&3 is resident for T+1's fill.    */\
        asm volatile("s_waitcnt vmcnt(4)" ::: "memory");                      \
        __builtin_amdgcn_s_barrier();                                         \
        __builtin_amdgcn_sched_barrier(0);                                    \
    } while (0)

    for (int tt = 0; tt < KSTEPS; tt += 2) {
        TILE(tt,     aP, bP, aQ, bQ);
        TILE(tt + 1, aQ, bQ, aP, bP);
    }
#undef TILE
#undef STAGE_A
#undef STAGE_B

    // epilogue: C/D layout col = lane&15, row = (lane>>4)*4 + reg
#pragma unroll
    for (int mi = 0; mi < 8; ++mi) {
#pragma unroll
        for (int j = 0; j < 4; ++j) {
            size_t row = (size_t)(bm + (wm << 7) + mi * 16 + fq * 4 + j);
            float* Crow = C + row * N_DIM + (bn + (wn << 6) + fr);
#pragma unroll
            for (int ni = 0; ni < 4; ++ni)
                Crow[ni * 16] = acc[mi][ni][j];
        }
    }
}

// ---------------- launch ----------------
extern "C" void kernel_launch(void* const* d_in, const int* in_sizes, int n_in,
                              void* d_out, int out_size, void* d_ws, size_t ws_size,
                              hipStream_t stream) {
    const float* x   = (const float*)d_in[0];
    const int*   wq  = (const int*)d_in[1];
    const float* wos = (const float*)d_in[2];
    const float* wis = (const float*)d_in[3];
    float* out = (float*)d_out;

    short* xb = (short*)d_ws;                                        // 64 MB
    short* wb = (short*)((char*)d_ws + (size_t)M_DIM * K_DIM * 2);   // 128 MB

    cast_x_kernel<<<(M_DIM * (size_t)K_DIM / 8) / 256, 256, 0, stream>>>(x, xb);
    dequant_w_kernel<<<(N_DIM * (size_t)K_DIM / 16) / 256, 256, 0, stream>>>(wq, wos, wis, wb);
    gemm_bt_kernel<<<(M_DIM / BM) * (N_DIM / BN), 512, 0, stream>>>(xb, wb, out);
}

// Round 19
// 1068.300 us; speedup vs baseline: 1.4464x; 1.0883x over previous
//
#include <hip/hip_runtime.h>
#include <hip/hip_bf16.h>
#include <stdint.h>
#include <stddef.h>

// ---------------- problem dims (fixed by setup_inputs) ----------------
#define M_DIM 8192
#define K_DIM 4096
#define N_DIM 16384

#define BM 256
#define BN 256
#define BK 32
#define KSTEPS (K_DIM / BK)     // 128 K-tiles
#define SLOT_SH (BM * BK)       // 8192 shorts = 16 KB per matrix per slot
#define NSLOT 4                 // ring; stage distance 3

typedef __attribute__((ext_vector_type(8))) short bf16x8;  // 8 bf16 = 4 VGPRs
typedef __attribute__((ext_vector_type(4))) float f32x4;
typedef __attribute__((ext_vector_type(4))) int   i32x4;

// fp32 -> bf16, round-to-nearest-even (inputs finite)
static __device__ __forceinline__ short f2bf(float f) {
    union { float f; uint32_t u; } v; v.f = f;
    uint32_t r = v.u + 0x7FFFu + ((v.u >> 16) & 1u);
    return (short)(r >> 16);
}

// FP4 E2M1 decode: low 3 bits magnitude code, bit 3 sign.
static __device__ __forceinline__ float e2m1(int v) {
    int e = (v >> 1) & 3;
    int m = v & 1;
    float mag = (e == 0) ? 0.5f * (float)m
                         : (float)(2 + m) * 0.25f * (float)(1 << e);
    return (v & 8) ? -mag : mag;
}

// async global->LDS, 16 bytes per lane; LDS dest is wave-uniform base + lane*16
static __device__ __forceinline__ void gload16(short* lds, const short* g) {
    __builtin_amdgcn_global_load_lds(
        (const __attribute__((address_space(1))) void*)g,
        (__attribute__((address_space(3))) void*)lds,
        16, 0, 0);
}

// ---------------- kernel 1: x fp32 -> bf16 ----------------
__global__ void cast_x_kernel(const float* __restrict__ x, short* __restrict__ xb) {
    size_t i = (size_t)blockIdx.x * 256 + threadIdx.x;   // one short8 per thread
    const float4* s = reinterpret_cast<const float4*>(x);
    float4 a = s[2 * i];
    float4 b = s[2 * i + 1];
    bf16x8 o;
    o[0] = f2bf(a.x); o[1] = f2bf(a.y); o[2] = f2bf(a.z); o[3] = f2bf(a.w);
    o[4] = f2bf(b.x); o[5] = f2bf(b.y); o[6] = f2bf(b.z); o[7] = f2bf(b.w);
    reinterpret_cast<bf16x8*>(xb)[i] = o;
}

// ---------------- kernel 2: dequant w_q -> bf16 [N, K] ----------------
__global__ void dequant_w_kernel(const int* __restrict__ wq,
                                 const float* __restrict__ wos,
                                 const float* __restrict__ wis,
                                 short* __restrict__ wb) {
    int tid = blockIdx.x * 256 + threadIdx.x;    // N*(K/16) = 4,194,304 total
    int n   = tid >> 8;                          // K/16 = 256 inner blocks per row
    int blk = tid & 255;
    float scale = wis[(n << 8) | blk] * wos[(n << 5) | (blk >> 3)];
    const i32x4* q = reinterpret_cast<const i32x4*>(wq + ((size_t)n << 11) + (blk << 3));
    i32x4 q0 = q[0], q1 = q[1];
    bf16x8 o0, o1;
#pragma unroll
    for (int j = 0; j < 4; ++j) {
        int c = q0[j];
        o0[2 * j]     = f2bf(e2m1(c & 15) * scale);         // even in-feature
        o0[2 * j + 1] = f2bf(e2m1((c >> 4) & 15) * scale);  // odd in-feature
    }
#pragma unroll
    for (int j = 0; j < 4; ++j) {
        int c = q1[j];
        o1[2 * j]     = f2bf(e2m1(c & 15) * scale);
        o1[2 * j + 1] = f2bf(e2m1((c >> 4) & 15) * scale);
    }
    bf16x8* dst = reinterpret_cast<bf16x8*>(wb) + 2 * (size_t)tid;
    dst[0] = o0;
    dst[1] = o1;
}

// ---------------- kernel 3: C[M,N] = A[M,K] * B[N,K]^T, bf16 in / fp32 out --
// R19 = R17/R18 skeleton (verified-correct full-tile read-ahead, 4-slot
// ring, vmcnt(4) counts audited) + WAVE ROLE-SPLIT DE-PHASING.
// R18 post-mortem: full-tile read-ahead (zero lgkm on MFMA path) was
// IDENTICAL to R15 -> lgkm latency is not the cost. Surviving model:
// barrier lockstep makes both waves on each SIMD burst ds_reads together,
// then MFMA together -> DS pipe (2816 cyc/CU/tile64) and matrix pipe (2483)
// alternate instead of overlapping; measured 5400 ~= serial sum.
// Fix: waves 0-3 (one per SIMD) run [fill-next -> MFMA] per tile; waves 4-7
// (the second wave on each SIMD) run [MFMA -> fill-next]. At any instant
// each SIMD has one wave feeding the DS pipe and one feeding the matrix
// pipe. Sync identical per wave: one s_barrier + one vmcnt(4) per tile
// (wave-uniform branch; all waves hit the same barrier count). Bank/fill/
// stage dataflow identical to R18 -- only intra-tile ORDER differs by group.
// Race audit (unchanged from R18): prologue vmcnt(4) drains stages 0,1;
// boundary vmcnt(4) drains stage(T+2) (issued one tile ago, counted, never
// 0); fills of slot (T+1)&3 are lgkm-complete by consumption at T+1 before
// staging into it at T+2. Group-B's MFMA-first consumes banks its own
// program order filled last tile; slot residency guaranteed by the same
// boundary waits. Wrap ops (tt>=125) dead data, race-free.
__global__ __launch_bounds__(512)
void gemm_bt_kernel(const short* __restrict__ A,
                    const short* __restrict__ B,
                    float* __restrict__ C) {
    __shared__ __align__(16) short As[NSLOT * SLOT_SH];   // 64 KB
    __shared__ __align__(16) short Bs[NSLOT * SLOT_SH];   // 64 KB

    // raster: each XCD owns an 8-wide n-stripe, n-fast (R3, FETCH-verified)
    int bid = blockIdx.x;
    int xcd = bid & 7;
    int idx = bid >> 3;          // 0..255
    int im  = idx >> 3;          // 0..31
    int in8 = idx & 7;           // 0..7
    int bm  = im << 8;
    int bn  = ((xcd << 3) + in8) << 8;

    int t    = threadIdx.x;
    int lane = t & 63;
    int w    = t >> 6;           // wave 0..7; SIMD = w & 3; role = w >> 2
    int wm   = w >> 2;           // 0..1
    int wn   = w & 3;            // 0..3
    int fr   = lane & 15;
    int fq   = lane >> 4;
    int wbase = w << 9;          // wave staging base (shorts): w * 512

    // staging: thread t covers row (t>>2) of each 128-row chunk, 16B slot t&3.
    // pre-swizzled global k-chunk = (t&3) ^ ((row>>1)&3)  (R4-verified, 0 conf)
    int gcol = (((t & 3) ^ ((t >> 3) & 3)) << 3);        // shorts
    const short* AgB = A + (size_t)(bm + (t >> 2)) * K_DIM + gcol;
    const short* BgB = B + (size_t)(bn + (t >> 2)) * K_DIM + gcol;

    // read-side swizzled slot (constant per lane): fq ^ ((fr>>1)&3)
    int slot = fq ^ ((fr >> 1) & 3);
    int aoff[8], boff[4];
#pragma unroll
    for (int mi = 0; mi < 8; ++mi)
        aoff[mi] = ((wm << 7) + mi * 16 + fr) * 4 + slot;
#pragma unroll
    for (int ni = 0; ni < 4; ++ni)
        boff[ni] = ((wn << 6) + ni * 16 + fr) * 4 + slot;

    f32x4 acc[8][4] = {};

    // one matrix K-tile = 16 KB = 2 gloads (512 thr x 16 B = 8 KB each)
#define STAGE_A(slot_, kt_)                                                   \
    do {                                                                      \
        const short* _s = AgB + (size_t)(kt_) * BK;                           \
        short* _d = As + (slot_) * SLOT_SH + wbase;                           \
        gload16(_d,        _s);                                               \
        gload16(_d + 4096, _s + (size_t)128 * K_DIM);                         \
    } while (0)
#define STAGE_B(slot_, kt_)                                                   \
    do {                                                                      \
        const short* _s = BgB + (size_t)(kt_) * BK;                           \
        short* _d = Bs + (slot_) * SLOT_SH + wbase;                           \
        gload16(_d,        _s);                                               \
        gload16(_d + 4096, _s + (size_t)128 * K_DIM);                         \
    } while (0)

#define FILL_LO(aN, bN, AfN, BfN)                                             \
    do {                                                                      \
        _Pragma("unroll")                                                     \
        for (int ni = 0; ni < 4; ++ni) bN[ni] = BfN[boff[ni]];                \
        _Pragma("unroll")                                                     \
        for (int mi = 0; mi < 4; ++mi) aN[mi] = AfN[aoff[mi]];                \
    } while (0)
#define FILL_HI(aN, AfN)                                                      \
    do {                                                                      \
        _Pragma("unroll")                                                     \
        for (int mi = 4; mi < 8; ++mi) aN[mi] = AfN[aoff[mi]];                \
    } while (0)
#define MFMA_LO(aC, bC)                                                       \
    do {                                                                      \
        __builtin_amdgcn_s_setprio(1);                                        \
        _Pragma("unroll")                                                     \
        for (int mi = 0; mi < 4; ++mi)                                        \
            _Pragma("unroll")                                                 \
            for (int ni = 0; ni < 4; ++ni)                                    \
                acc[mi][ni] = __builtin_amdgcn_mfma_f32_16x16x32_bf16(        \
                    aC[mi], bC[ni], acc[mi][ni], 0, 0, 0);                    \
        __builtin_amdgcn_s_setprio(0);                                        \
    } while (0)
#define MFMA_HI(aC, bC)                                                       \
    do {                                                                      \
        __builtin_amdgcn_s_setprio(1);                                        \
        _Pragma("unroll")                                                     \
        for (int mi = 4; mi < 8; ++mi)                                        \
            _Pragma("unroll")                                                 \
            for (int ni = 0; ni < 4; ++ni)                                    \
                acc[mi][ni] = __builtin_amdgcn_mfma_f32_16x16x32_bf16(        \
                    aC[mi], bC[ni], acc[mi][ni], 0, 0, 0);                    \
        __builtin_amdgcn_s_setprio(0);                                        \
    } while (0)
#define SB() __builtin_amdgcn_sched_barrier(0)
#define BOUNDARY()                                                            \
    do {                                                                      \
        asm volatile("s_waitcnt vmcnt(4)" ::: "memory");                      \
        __builtin_amdgcn_s_barrier();                                         \
        SB();                                                                 \
    } while (0)

    // group A (one wave per SIMD): fills first, MFMA after  (R18 order)
#define TILE_RD(tt, aC, bC, aN, bN)                                           \
    do {                                                                      \
        int ktn  = ((tt) + 3) & (KSTEPS - 1);                                 \
        int sStg = ((tt) + 3) & 3;                                            \
        const bf16x8* AfN = reinterpret_cast<const bf16x8*>(As + (((tt) + 1) & 3) * SLOT_SH); \
        const bf16x8* BfN = reinterpret_cast<const bf16x8*>(Bs + (((tt) + 1) & 3) * SLOT_SH); \
        STAGE_A(sStg, ktn);                                                   \
        FILL_LO(aN, bN, AfN, BfN);                                            \
        SB();                                                                 \
        MFMA_LO(aC, bC);                                                      \
        SB();                                                                 \
        STAGE_B(sStg, ktn);                                                   \
        FILL_HI(aN, AfN);                                                     \
        SB();                                                                 \
        MFMA_HI(aC, bC);                                                      \
        BOUNDARY();                                                           \
    } while (0)

    // group B (second wave per SIMD): MFMA first, fills after -> the two
    // waves on each SIMD feed different pipes at any instant.
#define TILE_MF(tt, aC, bC, aN, bN)                                           \
    do {                                                                      \
        int ktn  = ((tt) + 3) & (KSTEPS - 1);                                 \
        int sStg = ((tt) + 3) & 3;                                            \
        const bf16x8* AfN = reinterpret_cast<const bf16x8*>(As + (((tt) + 1) & 3) * SLOT_SH); \
        const bf16x8* BfN = reinterpret_cast<const bf16x8*>(Bs + (((tt) + 1) & 3) * SLOT_SH); \
        MFMA_LO(aC, bC);                                                      \
        SB();                                                                 \
        STAGE_A(sStg, ktn);                                                   \
        FILL_LO(aN, bN, AfN, BfN);                                            \
        SB();                                                                 \
        MFMA_HI(aC, bC);                                                      \
        SB();                                                                 \
        STAGE_B(sStg, ktn);                                                   \
        FILL_HI(aN, AfN);                                                     \
        BOUNDARY();                                                           \
    } while (0)

    // fragment banks: P consumed on even tiles, Q on odd (static names)
    bf16x8 aP[8], bP[4], aQ[8], bQ[4];

    // prologue: stage tiles 0,1,2 (12 loads); vmcnt(4) drains stages 0 AND 1
    // (tile 0 reads slot 0 now and slot 1 mid-tile); fill P with tile 0.
    STAGE_A(0, 0); STAGE_B(0, 0);
    STAGE_A(1, 1); STAGE_B(1, 1);
    STAGE_A(2, 2); STAGE_B(2, 2);
    asm volatile("s_waitcnt vmcnt(4)" ::: "memory");
    __builtin_amdgcn_s_barrier();
    {
        const bf16x8* Af = reinterpret_cast<const bf16x8*>(As);
        const bf16x8* Bf = reinterpret_cast<const bf16x8*>(Bs);
#pragma unroll
        for (int ni = 0; ni < 4; ++ni) bP[ni] = Bf[boff[ni]];
#pragma unroll
        for (int mi = 0; mi < 8; ++mi) aP[mi] = Af[aoff[mi]];
    }

    if (w < 4) {
        for (int tt = 0; tt < KSTEPS; tt += 2) {
            TILE_RD(tt,     aP, bP, aQ, bQ);
            TILE_RD(tt + 1, aQ, bQ, aP, bP);
        }
    } else {
        for (int tt = 0; tt < KSTEPS; tt += 2) {
            TILE_MF(tt,     aP, bP, aQ, bQ);
            TILE_MF(tt + 1, aQ, bQ, aP, bP);
        }
    }
#undef TILE_RD
#undef TILE_MF
#undef BOUNDARY
#undef SB
#undef MFMA_LO
#undef MFMA_HI
#undef FILL_LO
#undef FILL_HI
#undef STAGE_A
#undef STAGE_B

    // epilogue: C/D layout col = lane&15, row = (lane>>4)*4 + reg
#pragma unroll
    for (int mi = 0; mi < 8; ++mi) {
#pragma unroll
        for (int j = 0; j < 4; ++j) {
            size_t row = (size_t)(bm + (wm << 7) + mi * 16 + fq * 4 + j);
            float* Crow = C + row * N_DIM + (bn + (wn << 6) + fr);
#pragma unroll
            for (int ni = 0; ni < 4; ++ni)
                Crow[ni * 16] = acc[mi][ni][j];
        }
    }
}

// ---------------- launch ----------------
extern "C" void kernel_launch(void* const* d_in, const int* in_sizes, int n_in,
                              void* d_out, int out_size, void* d_ws, size_t ws_size,
                              hipStream_t stream) {
    const float* x   = (const float*)d_in[0];
    const int*   wq  = (const int*)d_in[1];
    const float* wos = (const float*)d_in[2];
    const float* wis = (const float*)d_in[3];
    float* out = (float*)d_out;

    short* xb = (short*)d_ws;                                        // 64 MB
    short* wb = (short*)((char*)d_ws + (size_t)M_DIM * K_DIM * 2);   // 128 MB

    cast_x_kernel<<<(M_DIM * (size_t)K_DIM / 8) / 256, 256, 0, stream>>>(x, xb);
    dequant_w_kernel<<<(N_DIM * (size_t)K_DIM / 16) / 256, 256, 0, stream>>>(wq, wos, wis, wb);
    gemm_bt_kernel<<<(M_DIM / BM) * (N_DIM / BN), 512, 0, stream>>>(xb, wb, out);
}